// Round 4
// baseline (1710.834 us; speedup 1.0000x reference)
//
#include <hip/hip_runtime.h>

#define TT 200
#define BB 1024
#define II 128
#define HH 128

// LDS layout (float offsets)
#define OFF_WC 0        // 32768 floats: Wc as [k/4][128][4]
#define OFF_XH 32768    // 1024: xh [4][256]
#define OFF_P  33792    // 4096: partial sums
#define OFF_SU 37888    // 512: u-gate sigmoid [4][128]
#define OFF_H  38400    // 512: h state [4][128]
#define OFF_A  38912    // 8: att scores
#define LDS_FLOATS 38920

// 1 block/CU (LDS-forced: 152KB). 16 waves/block = 4 waves/EU exactly; pin
// the register budget there (512/4 = 128 VGPRs) so wg4[16]x4 stays in regs.
// Round-2 evidence: default heuristic chose 64 VGPRs -> ~3 dword/thread/step
// scratch spill -> WRITE_SIZE 740MB vs 105MB of real output, dur 1528us.
extern "C" __global__ void __launch_bounds__(1024, 4)
gru_persist(const float* __restrict__ X, const float* __restrict__ ATT,
            const int* __restrict__ LEN, const float* __restrict__ Wg,
            const float* __restrict__ bgp, const float* __restrict__ Wcp,
            const float* __restrict__ bcp, float* __restrict__ OUT) {
  extern __shared__ float sm[];
  float* lWc = sm + OFF_WC;
  float* lxh = sm + OFF_XH;
  float* lp  = sm + OFF_P;
  float* lsu = sm + OFF_SU;
  float* lh  = sm + OFF_H;
  float* la  = sm + OFF_A;

  const int tid  = threadIdx.x;
  const int row0 = blockIdx.x << 2;   // 4 rows per WG

  // Stage Wc into LDS: lWc[(k>>2)][jc][k&3]  (one-time)
  for (int idx = tid; idx < 128 * 256; idx += 1024) {
    const int jcol = idx >> 8;
    const int k    = idx & 255;
    lWc[((k >> 2) << 9) + (jcol << 2) + (k & 3)] = Wcp[idx];
  }
  if (tid < 512) lh[tid] = 0.0f;

  // gate mapping: j = output col (0..255), kq = k-quarter (wave-uniform)
  const int j   = tid & 255;
  const int kq  = tid >> 8;
  // candidate / phase4 mapping: jc = col (0..127), kq8 = k-eighth (wave-uniform)
  const int jc  = tid & 127;
  const int kq8 = tid >> 7;
  const int r4  = kq8;   // row index for tid<512 roles

  // Gate weights resident in VGPRs: Wg[j][kq*64 .. kq*64+63]
  float4 wg4[16];
  {
    const float4* wrow = (const float4*)(Wg + (j << 8) + (kq << 6));
#pragma unroll
    for (int c = 0; c < 16; ++c) wg4[c] = wrow[c];
  }
  const float bgj = bgp[j];
  const float bcj = bcp[jc];

  const int l0 = LEN[row0 + 0], l1 = LEN[row0 + 1];
  const int l2 = LEN[row0 + 2], l3 = LEN[row0 + 3];
  int maxlen = max(max(l0, l1), max(l2, l3));
  if (maxlen > TT) maxlen = TT;
  const int mylen = (r4 == 0) ? l0 : (r4 == 1) ? l1 : (r4 == 2) ? l2 : l3;

  // prefetch x[0], att[0]
  float xn = 0.0f, an = 0.0f;
  if (tid < 512) xn = X[((row0 + r4) << 7) + jc];
  if (tid < 4)   an = ATT[row0 + tid];

  __syncthreads();

  for (int t = 0; t < maxlen; ++t) {
    // ---- phase0: build xh = [x, h] ----
    if (tid < 512) {
      lxh[(r4 << 8) + jc] = xn;
    } else {
      const int rr = (tid >> 7) - 4;
      lxh[(rr << 8) + 128 + jc] = lh[(rr << 7) + jc];
    }
    if (tid < 4) la[tid] = an;
    __syncthreads();

    // issue next-step prefetch early; latency hides under the FMA phases
    if (t + 1 < TT) {
      if (tid < 512) xn = X[((((t + 1) << 10) + row0 + r4) << 7) + jc];
      if (tid < 4)   an = ATT[((t + 1) << 10) + row0 + tid];
    }

    // ---- phase1: gate matvec partials (weights in VGPR, xh broadcast) ----
    {
      float a0 = 0.f, a1 = 0.f, a2 = 0.f, a3 = 0.f;
      const float4* p0 = (const float4*)(lxh + (kq << 6));
      const float4* p1 = (const float4*)(lxh + 256 + (kq << 6));
      const float4* p2 = (const float4*)(lxh + 512 + (kq << 6));
      const float4* p3 = (const float4*)(lxh + 768 + (kq << 6));
#pragma unroll
      for (int c = 0; c < 16; ++c) {
        const float4 w = wg4[c];
        const float4 v0 = p0[c];
        a0 = __builtin_fmaf(w.x, v0.x, a0); a0 = __builtin_fmaf(w.y, v0.y, a0);
        a0 = __builtin_fmaf(w.z, v0.z, a0); a0 = __builtin_fmaf(w.w, v0.w, a0);
        const float4 v1 = p1[c];
        a1 = __builtin_fmaf(w.x, v1.x, a1); a1 = __builtin_fmaf(w.y, v1.y, a1);
        a1 = __builtin_fmaf(w.z, v1.z, a1); a1 = __builtin_fmaf(w.w, v1.w, a1);
        const float4 v2 = p2[c];
        a2 = __builtin_fmaf(w.x, v2.x, a2); a2 = __builtin_fmaf(w.y, v2.y, a2);
        a2 = __builtin_fmaf(w.z, v2.z, a2); a2 = __builtin_fmaf(w.w, v2.w, a2);
        const float4 v3 = p3[c];
        a3 = __builtin_fmaf(w.x, v3.x, a3); a3 = __builtin_fmaf(w.y, v3.y, a3);
        a3 = __builtin_fmaf(w.z, v3.z, a3); a3 = __builtin_fmaf(w.w, v3.w, a3);
      }
      // lp[r][kq][j] — lane-consecutive stores, conflict-free
      lp[(kq << 8) + j]        = a0;
      lp[((4 + kq) << 8) + j]  = a1;
      lp[((8 + kq) << 8) + j]  = a2;
      lp[((12 + kq) << 8) + j] = a3;
    }
    __syncthreads();

    // ---- phase2: reduce + sigmoid; build r*h into xh ----
    {
      const int r2 = kq;           // tid>>8
      const int base = r2 << 10;
      float s = lp[base + j] + lp[base + 256 + j] +
                lp[base + 512 + j] + lp[base + 768 + j] + bgj;
      const float sig = 1.0f / (1.0f + __expf(-s));
      if (j < 128) lxh[(r2 << 8) + 128 + j] = sig * lh[(r2 << 7) + j];
      else         lsu[(r2 << 7) + (j - 128)] = sig;
    }
    __syncthreads();

    // ---- phase3: candidate matvec partials (Wc from LDS) ----
    {
      float a0 = 0.f, a1 = 0.f, a2 = 0.f, a3 = 0.f;
      const int kb = kq8 << 5;
      const float4* p0 = (const float4*)(lxh + kb);
      const float4* p1 = (const float4*)(lxh + 256 + kb);
      const float4* p2 = (const float4*)(lxh + 512 + kb);
      const float4* p3 = (const float4*)(lxh + 768 + kb);
      const float4* wp = (const float4*)(lWc + ((kb >> 2) << 9) + (jc << 2));
#pragma unroll
      for (int c = 0; c < 8; ++c) {
        const float4 w = wp[c << 7];   // + c*512 floats
        const float4 v0 = p0[c];
        a0 = __builtin_fmaf(w.x, v0.x, a0); a0 = __builtin_fmaf(w.y, v0.y, a0);
        a0 = __builtin_fmaf(w.z, v0.z, a0); a0 = __builtin_fmaf(w.w, v0.w, a0);
        const float4 v1 = p1[c];
        a1 = __builtin_fmaf(w.x, v1.x, a1); a1 = __builtin_fmaf(w.y, v1.y, a1);
        a1 = __builtin_fmaf(w.z, v1.z, a1); a1 = __builtin_fmaf(w.w, v1.w, a1);
        const float4 v2 = p2[c];
        a2 = __builtin_fmaf(w.x, v2.x, a2); a2 = __builtin_fmaf(w.y, v2.y, a2);
        a2 = __builtin_fmaf(w.z, v2.z, a2); a2 = __builtin_fmaf(w.w, v2.w, a2);
        const float4 v3 = p3[c];
        a3 = __builtin_fmaf(w.x, v3.x, a3); a3 = __builtin_fmaf(w.y, v3.y, a3);
        a3 = __builtin_fmaf(w.z, v3.z, a3); a3 = __builtin_fmaf(w.w, v3.w, a3);
      }
      // lp[r][kq8][jc]
      lp[(kq8 << 7) + jc]        = a0;
      lp[((8 + kq8) << 7) + jc]  = a1;
      lp[((16 + kq8) << 7) + jc] = a2;
      lp[((24 + kq8) << 7) + jc] = a3;
    }
    __syncthreads();

    // ---- phase4: reduce + tanh + state update + output ----
    if (tid < 512) {
      const int base = r4 << 10;
      float s = bcj;
#pragma unroll
      for (int q = 0; q < 8; ++q) s += lp[base + (q << 7) + jc];
      const float e2 = __expf(2.0f * s);
      const float cc = (e2 - 1.0f) / (e2 + 1.0f);
      const float u  = (1.0f - la[r4]) * lsu[(r4 << 7) + jc];
      const float hold = lh[(r4 << 7) + jc];
      const float nh = u * hold + (1.0f - u) * cc;
      const bool m = (t < mylen);
      lh[(r4 << 7) + jc] = m ? nh : hold;
      OUT[(((t << 10) + row0 + r4) << 7) + jc] = m ? nh : 0.0f;
    }
    __syncthreads();
  }

  // zero-fill steps past maxlen (harness poisons d_out)
  for (int t = maxlen; t < TT; ++t) {
    if (tid < 128) {
      const int rr = tid >> 5;
      const int qq = tid & 31;
      *(float4*)(OUT + (((t << 10) + row0 + rr) << 7) + (qq << 2)) =
          make_float4(0.f, 0.f, 0.f, 0.f);
    }
  }
  // final hidden state hx at offset T*B*H
  if (tid < 512) {
    OUT[TT * BB * HH + ((row0 + r4) << 7) + jc] = lh[(r4 << 7) + jc];
  }
}

extern "C" void kernel_launch(void* const* d_in, const int* in_sizes, int n_in,
                              void* d_out, int out_size, void* d_ws, size_t ws_size,
                              hipStream_t stream) {
  const float* X   = (const float*)d_in[0];
  const float* ATT = (const float*)d_in[1];
  const int*   LEN = (const int*)d_in[2];
  const float* Wg  = (const float*)d_in[3];
  const float* bg  = (const float*)d_in[4];
  const float* Wc  = (const float*)d_in[5];
  const float* bc  = (const float*)d_in[6];
  float* OUT = (float*)d_out;

  const size_t shmem = (size_t)LDS_FLOATS * sizeof(float);
  static_assert(LDS_FLOATS * sizeof(float) <= 160 * 1024, "LDS over 160KiB");
  (void)hipFuncSetAttribute((const void*)gru_persist,
                            hipFuncAttributeMaxDynamicSharedMemorySize,
                            (int)shmem);
  gru_persist<<<dim3(256), dim3(1024), shmem, stream>>>(X, ATT, LEN, Wg, bg,
                                                        Wc, bc, OUT);
}

// Round 5
// 1582.224 us; speedup vs baseline: 1.0813x; 1.0813x over previous
//
#include <hip/hip_runtime.h>

#define TT 200
#define BB 1024
#define II 128
#define HH 128

// LDS layout (float offsets)
#define OFF_WC 0        // 32768 floats: Wc as [k/4][128][4]
#define OFF_XH 32768    // 1024: xh [4][256]
#define OFF_P  33792    // 4096: partial sums
#define OFF_SU 37888    // 512: u-gate sigmoid [4][128]
#define OFF_H  38400    // 512: h state [4][128]
#define OFF_A  38912    // 8: att scores
#define LDS_FLOATS 38920

// 1 block/CU (LDS-forced: 152KB). 16 waves/block = 4 waves/EU exactly.
// amdgpu_waves_per_eu(4,4) pins min AND max occupancy: budget = 512/4 = 128
// VGPRs and — critically — the scheduler stops spilling to chase 8 waves/EU.
// Round-4 evidence: __launch_bounds__(1024,4) (min-only) still allocated 64
// VGPRs and spilled (WRITE_SIZE 836MB vs 105MB real output, dur 1660us).
extern "C" __global__ void
__attribute__((amdgpu_flat_work_group_size(1024, 1024), amdgpu_waves_per_eu(4, 4)))
gru_persist(const float* __restrict__ X, const float* __restrict__ ATT,
            const int* __restrict__ LEN, const float* __restrict__ Wg,
            const float* __restrict__ bgp, const float* __restrict__ Wcp,
            const float* __restrict__ bcp, float* __restrict__ OUT) {
  extern __shared__ float sm[];
  float* lWc = sm + OFF_WC;
  float* lxh = sm + OFF_XH;
  float* lp  = sm + OFF_P;
  float* lsu = sm + OFF_SU;
  float* lh  = sm + OFF_H;
  float* la  = sm + OFF_A;

  const int tid  = threadIdx.x;
  const int row0 = blockIdx.x << 2;   // 4 rows per WG

  // Stage Wc into LDS: lWc[(k>>2)][jc][k&3]  (one-time)
  for (int idx = tid; idx < 128 * 256; idx += 1024) {
    const int jcol = idx >> 8;
    const int k    = idx & 255;
    lWc[((k >> 2) << 9) + (jcol << 2) + (k & 3)] = Wcp[idx];
  }
  if (tid < 512) lh[tid] = 0.0f;

  // gate mapping: j = output col (0..255), kq = k-quarter (wave-uniform)
  const int j   = tid & 255;
  const int kq  = tid >> 8;
  // candidate / phase4 mapping: jc = col (0..127), kq8 = k-eighth (wave-uniform)
  const int jc  = tid & 127;
  const int kq8 = tid >> 7;
  const int r4  = kq8;   // row index for tid<512 roles

  // Gate weights resident in VGPRs: Wg[j][kq*64 .. kq*64+63]
  float4 wg4[16];
  {
    const float4* wrow = (const float4*)(Wg + (j << 8) + (kq << 6));
#pragma unroll
    for (int c = 0; c < 16; ++c) wg4[c] = wrow[c];
  }
  const float bgj = bgp[j];
  const float bcj = bcp[jc];

  const int l0 = LEN[row0 + 0], l1 = LEN[row0 + 1];
  const int l2 = LEN[row0 + 2], l3 = LEN[row0 + 3];
  int maxlen = max(max(l0, l1), max(l2, l3));
  if (maxlen > TT) maxlen = TT;
  const int mylen = (r4 == 0) ? l0 : (r4 == 1) ? l1 : (r4 == 2) ? l2 : l3;

  // prefetch x[0], att[0]
  float xn = 0.0f, an = 0.0f;
  if (tid < 512) xn = X[((row0 + r4) << 7) + jc];
  if (tid < 4)   an = ATT[row0 + tid];

  __syncthreads();

  for (int t = 0; t < maxlen; ++t) {
    // ---- phase0: build xh = [x, h] ----
    if (tid < 512) {
      lxh[(r4 << 8) + jc] = xn;
    } else {
      const int rr = (tid >> 7) - 4;
      lxh[(rr << 8) + 128 + jc] = lh[(rr << 7) + jc];
    }
    if (tid < 4) la[tid] = an;
    __syncthreads();

    // issue next-step prefetch early; latency hides under the FMA phases
    if (t + 1 < TT) {
      if (tid < 512) xn = X[((((t + 1) << 10) + row0 + r4) << 7) + jc];
      if (tid < 4)   an = ATT[((t + 1) << 10) + row0 + tid];
    }

    // ---- phase1: gate matvec partials (weights in VGPR, xh broadcast) ----
    {
      float a0 = 0.f, a1 = 0.f, a2 = 0.f, a3 = 0.f;
      const float4* p0 = (const float4*)(lxh + (kq << 6));
      const float4* p1 = (const float4*)(lxh + 256 + (kq << 6));
      const float4* p2 = (const float4*)(lxh + 512 + (kq << 6));
      const float4* p3 = (const float4*)(lxh + 768 + (kq << 6));
#pragma unroll
      for (int c = 0; c < 16; ++c) {
        const float4 w = wg4[c];
        const float4 v0 = p0[c]; a0 += w.x*v0.x + w.y*v0.y + w.z*v0.z + w.w*v0.w;
        const float4 v1 = p1[c]; a1 += w.x*v1.x + w.y*v1.y + w.z*v1.z + w.w*v1.w;
        const float4 v2 = p2[c]; a2 += w.x*v2.x + w.y*v2.y + w.z*v2.z + w.w*v2.w;
        const float4 v3 = p3[c]; a3 += w.x*v3.x + w.y*v3.y + w.z*v3.z + w.w*v3.w;
      }
      // lp[r][kq][j] — lane-consecutive stores, conflict-free
      lp[(kq << 8) + j]        = a0;
      lp[((4 + kq) << 8) + j]  = a1;
      lp[((8 + kq) << 8) + j]  = a2;
      lp[((12 + kq) << 8) + j] = a3;
    }
    __syncthreads();

    // ---- phase2: reduce + sigmoid; build r*h into xh ----
    {
      const int r2 = kq;           // tid>>8
      const int base = r2 << 10;
      float s = lp[base + j] + lp[base + 256 + j] +
                lp[base + 512 + j] + lp[base + 768 + j] + bgj;
      const float sig = 1.0f / (1.0f + __expf(-s));
      if (j < 128) lxh[(r2 << 8) + 128 + j] = sig * lh[(r2 << 7) + j];
      else         lsu[(r2 << 7) + (j - 128)] = sig;
    }
    __syncthreads();

    // ---- phase3: candidate matvec partials (Wc from LDS) ----
    {
      float a0 = 0.f, a1 = 0.f, a2 = 0.f, a3 = 0.f;
      const int kb = kq8 << 5;
      const float4* p0 = (const float4*)(lxh + kb);
      const float4* p1 = (const float4*)(lxh + 256 + kb);
      const float4* p2 = (const float4*)(lxh + 512 + kb);
      const float4* p3 = (const float4*)(lxh + 768 + kb);
      const float4* wp = (const float4*)(lWc + ((kb >> 2) << 9) + (jc << 2));
#pragma unroll
      for (int c = 0; c < 8; ++c) {
        const float4 w = wp[c << 7];   // + c*512 floats
        const float4 v0 = p0[c]; a0 += w.x*v0.x + w.y*v0.y + w.z*v0.z + w.w*v0.w;
        const float4 v1 = p1[c]; a1 += w.x*v1.x + w.y*v1.y + w.z*v1.z + w.w*v1.w;
        const float4 v2 = p2[c]; a2 += w.x*v2.x + w.y*v2.y + w.z*v2.z + w.w*v2.w;
        const float4 v3 = p3[c]; a3 += w.x*v3.x + w.y*v3.y + w.z*v3.z + w.w*v3.w;
      }
      // lp[r][kq8][jc]
      lp[(kq8 << 7) + jc]        = a0;
      lp[((8 + kq8) << 7) + jc]  = a1;
      lp[((16 + kq8) << 7) + jc] = a2;
      lp[((24 + kq8) << 7) + jc] = a3;
    }
    __syncthreads();

    // ---- phase4: reduce + tanh + state update + output ----
    if (tid < 512) {
      const int base = r4 << 10;
      float s = bcj;
#pragma unroll
      for (int q = 0; q < 8; ++q) s += lp[base + (q << 7) + jc];
      const float e2 = __expf(2.0f * s);
      const float cc = (e2 - 1.0f) / (e2 + 1.0f);
      const float u  = (1.0f - la[r4]) * lsu[(r4 << 7) + jc];
      const float hold = lh[(r4 << 7) + jc];
      const float nh = u * hold + (1.0f - u) * cc;
      const bool m = (t < mylen);
      lh[(r4 << 7) + jc] = m ? nh : hold;
      OUT[(((t << 10) + row0 + r4) << 7) + jc] = m ? nh : 0.0f;
    }
    __syncthreads();
  }

  // zero-fill steps past maxlen (harness poisons d_out)
  for (int t = maxlen; t < TT; ++t) {
    if (tid < 128) {
      const int rr = tid >> 5;
      const int qq = tid & 31;
      *(float4*)(OUT + (((t << 10) + row0 + rr) << 7) + (qq << 2)) =
          make_float4(0.f, 0.f, 0.f, 0.f);
    }
  }
  // final hidden state hx at offset T*B*H
  if (tid < 512) {
    OUT[TT * BB * HH + ((row0 + r4) << 7) + jc] = lh[(r4 << 7) + jc];
  }
}

extern "C" void kernel_launch(void* const* d_in, const int* in_sizes, int n_in,
                              void* d_out, int out_size, void* d_ws, size_t ws_size,
                              hipStream_t stream) {
  const float* X   = (const float*)d_in[0];
  const float* ATT = (const float*)d_in[1];
  const int*   LEN = (const int*)d_in[2];
  const float* Wg  = (const float*)d_in[3];
  const float* bg  = (const float*)d_in[4];
  const float* Wc  = (const float*)d_in[5];
  const float* bc  = (const float*)d_in[6];
  float* OUT = (float*)d_out;

  const size_t shmem = (size_t)LDS_FLOATS * sizeof(float);
  static_assert(LDS_FLOATS * sizeof(float) <= 160 * 1024, "LDS over 160KiB");
  (void)hipFuncSetAttribute((const void*)gru_persist,
                            hipFuncAttributeMaxDynamicSharedMemorySize,
                            (int)shmem);
  gru_persist<<<dim3(256), dim3(1024), shmem, stream>>>(X, ATT, LEN, Wg, bg,
                                                        Wc, bc, OUT);
}

// Round 7
// 1581.284 us; speedup vs baseline: 1.0819x; 1.0006x over previous
//
#include <hip/hip_runtime.h>

#define TT 200
#define BB 1024
#define II 128
#define HH 128

// LDS layout (float offsets)
#define OFF_WC 0        // 32768 floats: Wc as [k/4][128][4]
#define OFF_XH 32768    // 1024: xh [4][256]
#define OFF_P  33792    // 4096: partial sums
#define OFF_SU 37888    // 512: u-gate sigmoid [4][128]
#define OFF_H  38400    // 512: h state [4][128]
#define OFF_A  38912    // 8: att scores
#define LDS_FLOATS 38920

// 1 block/CU (LDS-forced: 152KB) -> 16 waves = 4 waves/EU; 128 VGPRs/wave is
// exactly the 512-reg/SIMD file. History:
//   r2: no attrs            -> VGPR 64, spill, WRITE 740MB, 1528us
//   r4: launch_bounds(,4)   -> VGPR 64 (min-only, no effect), 1660us
//   r5: waves_per_eu(4,4)   -> SGPR changed (attr applied!) but VGPR still 64
// => occupancy hints don't raise the budget; amdgpu_num_vgpr(128) overrides
// the backend's computed max directly. (r6 = this kernel, infra timeout.)
extern "C" __global__ void
__attribute__((amdgpu_flat_work_group_size(1024, 1024),
               amdgpu_waves_per_eu(4, 4),
               amdgpu_num_vgpr(128)))
gru_persist(const float* __restrict__ X, const float* __restrict__ ATT,
            const int* __restrict__ LEN, const float* __restrict__ Wg,
            const float* __restrict__ bgp, const float* __restrict__ Wcp,
            const float* __restrict__ bcp, float* __restrict__ OUT) {
  extern __shared__ float sm[];
  float* lWc = sm + OFF_WC;
  float* lxh = sm + OFF_XH;
  float* lp  = sm + OFF_P;
  float* lsu = sm + OFF_SU;
  float* lh  = sm + OFF_H;
  float* la  = sm + OFF_A;

  const int tid  = threadIdx.x;
  const int row0 = blockIdx.x << 2;   // 4 rows per WG

  // Stage Wc into LDS: lWc[(k>>2)][jc][k&3]  (one-time)
  for (int idx = tid; idx < 128 * 256; idx += 1024) {
    const int jcol = idx >> 8;
    const int k    = idx & 255;
    lWc[((k >> 2) << 9) + (jcol << 2) + (k & 3)] = Wcp[idx];
  }
  if (tid < 512) lh[tid] = 0.0f;

  // gate mapping: j = output col (0..255), kq = k-quarter (wave-uniform)
  const int j   = tid & 255;
  const int kq  = tid >> 8;
  // candidate / phase4 mapping: jc = col (0..127), kq8 = k-eighth (wave-uniform)
  const int jc  = tid & 127;
  const int kq8 = tid >> 7;
  const int r4  = kq8;   // row index for tid<512 roles

  // Gate weights resident in VGPRs: Wg[j][kq*64 .. kq*64+63]
  float4 wg4[16];
  {
    const float4* wrow = (const float4*)(Wg + (j << 8) + (kq << 6));
#pragma unroll
    for (int c = 0; c < 16; ++c) wg4[c] = wrow[c];
  }
  const float bgj = bgp[j];
  const float bcj = bcp[jc];

  const int l0 = LEN[row0 + 0], l1 = LEN[row0 + 1];
  const int l2 = LEN[row0 + 2], l3 = LEN[row0 + 3];
  int maxlen = max(max(l0, l1), max(l2, l3));
  if (maxlen > TT) maxlen = TT;
  const int mylen = (r4 == 0) ? l0 : (r4 == 1) ? l1 : (r4 == 2) ? l2 : l3;

  // prefetch x[0], att[0]
  float xn = 0.0f, an = 0.0f;
  if (tid < 512) xn = X[((row0 + r4) << 7) + jc];
  if (tid < 4)   an = ATT[row0 + tid];

  __syncthreads();

  for (int t = 0; t < maxlen; ++t) {
    // ---- phase0: build xh = [x, h] ----
    if (tid < 512) {
      lxh[(r4 << 8) + jc] = xn;
    } else {
      const int rr = (tid >> 7) - 4;
      lxh[(rr << 8) + 128 + jc] = lh[(rr << 7) + jc];
    }
    if (tid < 4) la[tid] = an;
    __syncthreads();

    // issue next-step prefetch early; latency hides under the FMA phases
    if (t + 1 < TT) {
      if (tid < 512) xn = X[((((t + 1) << 10) + row0 + r4) << 7) + jc];
      if (tid < 4)   an = ATT[((t + 1) << 10) + row0 + tid];
    }

    // ---- phase1: gate matvec partials (weights in VGPR, xh broadcast) ----
    {
      float a0 = 0.f, a1 = 0.f, a2 = 0.f, a3 = 0.f;
      const float4* p0 = (const float4*)(lxh + (kq << 6));
      const float4* p1 = (const float4*)(lxh + 256 + (kq << 6));
      const float4* p2 = (const float4*)(lxh + 512 + (kq << 6));
      const float4* p3 = (const float4*)(lxh + 768 + (kq << 6));
#pragma unroll
      for (int c = 0; c < 16; ++c) {
        const float4 w = wg4[c];
        const float4 v0 = p0[c]; a0 += w.x*v0.x + w.y*v0.y + w.z*v0.z + w.w*v0.w;
        const float4 v1 = p1[c]; a1 += w.x*v1.x + w.y*v1.y + w.z*v1.z + w.w*v1.w;
        const float4 v2 = p2[c]; a2 += w.x*v2.x + w.y*v2.y + w.z*v2.z + w.w*v2.w;
        const float4 v3 = p3[c]; a3 += w.x*v3.x + w.y*v3.y + w.z*v3.z + w.w*v3.w;
      }
      // lp[r][kq][j] — lane-consecutive stores, conflict-free
      lp[(kq << 8) + j]        = a0;
      lp[((4 + kq) << 8) + j]  = a1;
      lp[((8 + kq) << 8) + j]  = a2;
      lp[((12 + kq) << 8) + j] = a3;
    }
    __syncthreads();

    // ---- phase2: reduce + sigmoid; build r*h into xh ----
    {
      const int r2 = kq;           // tid>>8
      const int base = r2 << 10;
      float s = lp[base + j] + lp[base + 256 + j] +
                lp[base + 512 + j] + lp[base + 768 + j] + bgj;
      const float sig = 1.0f / (1.0f + __expf(-s));
      if (j < 128) lxh[(r2 << 8) + 128 + j] = sig * lh[(r2 << 7) + j];
      else         lsu[(r2 << 7) + (j - 128)] = sig;
    }
    __syncthreads();

    // ---- phase3: candidate matvec partials (Wc from LDS) ----
    {
      float a0 = 0.f, a1 = 0.f, a2 = 0.f, a3 = 0.f;
      const int kb = kq8 << 5;
      const float4* p0 = (const float4*)(lxh + kb);
      const float4* p1 = (const float4*)(lxh + 256 + kb);
      const float4* p2 = (const float4*)(lxh + 512 + kb);
      const float4* p3 = (const float4*)(lxh + 768 + kb);
      const float4* wp = (const float4*)(lWc + ((kb >> 2) << 9) + (jc << 2));
#pragma unroll
      for (int c = 0; c < 8; ++c) {
        const float4 w = wp[c << 7];   // + c*512 floats
        const float4 v0 = p0[c]; a0 += w.x*v0.x + w.y*v0.y + w.z*v0.z + w.w*v0.w;
        const float4 v1 = p1[c]; a1 += w.x*v1.x + w.y*v1.y + w.z*v1.z + w.w*v1.w;
        const float4 v2 = p2[c]; a2 += w.x*v2.x + w.y*v2.y + w.z*v2.z + w.w*v2.w;
        const float4 v3 = p3[c]; a3 += w.x*v3.x + w.y*v3.y + w.z*v3.z + w.w*v3.w;
      }
      // lp[r][kq8][jc]
      lp[(kq8 << 7) + jc]        = a0;
      lp[((8 + kq8) << 7) + jc]  = a1;
      lp[((16 + kq8) << 7) + jc] = a2;
      lp[((24 + kq8) << 7) + jc] = a3;
    }
    __syncthreads();

    // ---- phase4: reduce + tanh + state update + output ----
    if (tid < 512) {
      const int base = r4 << 10;
      float s = bcj;
#pragma unroll
      for (int q = 0; q < 8; ++q) s += lp[base + (q << 7) + jc];
      const float e2 = __expf(2.0f * s);
      const float cc = (e2 - 1.0f) / (e2 + 1.0f);
      const float u  = (1.0f - la[r4]) * lsu[(r4 << 7) + jc];
      const float hold = lh[(r4 << 7) + jc];
      const float nh = u * hold + (1.0f - u) * cc;
      const bool m = (t < mylen);
      lh[(r4 << 7) + jc] = m ? nh : hold;
      OUT[(((t << 10) + row0 + r4) << 7) + jc] = m ? nh : 0.0f;
    }
    __syncthreads();
  }

  // zero-fill steps past maxlen (harness poisons d_out)
  for (int t = maxlen; t < TT; ++t) {
    if (tid < 128) {
      const int rr = tid >> 5;
      const int qq = tid & 31;
      *(float4*)(OUT + (((t << 10) + row0 + rr) << 7) + (qq << 2)) =
          make_float4(0.f, 0.f, 0.f, 0.f);
    }
  }
  // final hidden state hx at offset T*B*H
  if (tid < 512) {
    OUT[TT * BB * HH + ((row0 + r4) << 7) + jc] = lh[(r4 << 7) + jc];
  }
}

extern "C" void kernel_launch(void* const* d_in, const int* in_sizes, int n_in,
                              void* d_out, int out_size, void* d_ws, size_t ws_size,
                              hipStream_t stream) {
  const float* X   = (const float*)d_in[0];
  const float* ATT = (const float*)d_in[1];
  const int*   LEN = (const int*)d_in[2];
  const float* Wg  = (const float*)d_in[3];
  const float* bg  = (const float*)d_in[4];
  const float* Wc  = (const float*)d_in[5];
  const float* bc  = (const float*)d_in[6];
  float* OUT = (float*)d_out;

  const size_t shmem = (size_t)LDS_FLOATS * sizeof(float);
  static_assert(LDS_FLOATS * sizeof(float) <= 160 * 1024, "LDS over 160KiB");
  (void)hipFuncSetAttribute((const void*)gru_persist,
                            hipFuncAttributeMaxDynamicSharedMemorySize,
                            (int)shmem);
  gru_persist<<<dim3(256), dim3(1024), shmem, stream>>>(X, ATT, LEN, Wg, bg,
                                                        Wc, bc, OUT);
}

// Round 10
// 1206.747 us; speedup vs baseline: 1.4177x; 1.3104x over previous
//
#include <hip/hip_runtime.h>

#define TT 200
#define BB 1024
#define II 128
#define HH 128

// LDS layout (float offsets)
#define OFF_WC 0        // 32768 floats: Wc as [k/4][128][4]
#define OFF_XH 32768    // 1024: xh [4][256]
#define OFF_P  33792    // 4096: partial sums
#define OFF_SU 37888    // 512: u-gate sigmoid [4][128]
#define OFF_H  38400    // 512: h state [4][128]
#define OFF_A  38912    // 8: att scores
#define LDS_FLOATS 38920

// History of the VGPR-budget fight (all verified by rocprof):
//   r2: no attrs          -> VGPR 64, scratch spill, WRITE 740MB, 1528us
//   r4: launch_bounds(,4) -> VGPR 64 (min-only, no effect), 1660us
//   r5: waves_per_eu(4,4) -> attr applied (SGPR 48->112) but VGPR still 64
//   r7: + amdgpu_num_vgpr(128) -> still 64. Heuristic immovable.
// Fix: hard-allocate the 64 weight floats in AGPRs via inline-asm "a"
// constraints (v_accvgpr_write/read). Asm is a hard constraint, not a hint:
// total regs ~= 64 AGPR + ~50 VGPR <= 128 -> 4 waves/SIMD (the LDS-forced
// occupancy anyway), and the VGPR side regains its full 64 for the loop.
// (r8, r9 = this kernel, infra acquisition timeouts — never ran.)
extern "C" __global__ void
__attribute__((amdgpu_flat_work_group_size(1024, 1024), amdgpu_waves_per_eu(4, 4)))
gru_persist(const float* __restrict__ X, const float* __restrict__ ATT,
            const int* __restrict__ LEN, const float* __restrict__ Wg,
            const float* __restrict__ bgp, const float* __restrict__ Wcp,
            const float* __restrict__ bcp, float* __restrict__ OUT) {
  extern __shared__ float sm[];
  float* lWc = sm + OFF_WC;
  float* lxh = sm + OFF_XH;
  float* lp  = sm + OFF_P;
  float* lsu = sm + OFF_SU;
  float* lh  = sm + OFF_H;
  float* la  = sm + OFF_A;

  const int tid  = threadIdx.x;
  const int row0 = blockIdx.x << 2;   // 4 rows per WG

  // Stage Wc into LDS: lWc[(k>>2)][jc][k&3]  (one-time)
  for (int idx = tid; idx < 128 * 256; idx += 1024) {
    const int jcol = idx >> 8;
    const int k    = idx & 255;
    lWc[((k >> 2) << 9) + (jcol << 2) + (k & 3)] = Wcp[idx];
  }
  if (tid < 512) lh[tid] = 0.0f;

  // gate mapping: j = output col (0..255), kq = k-quarter (wave-uniform)
  const int j   = tid & 255;
  const int kq  = tid >> 8;
  // candidate / phase4 mapping: jc = col (0..127), kq8 = k-eighth (wave-uniform)
  const int jc  = tid & 127;
  const int kq8 = tid >> 7;
  const int r4  = kq8;   // row index for tid<512 roles

  // Gate weights hard-pinned in AGPRs: Wg[j][kq*64 .. kq*64+63]
  float wg_a[64];
  {
    const float4* wrow = (const float4*)(Wg + (j << 8) + (kq << 6));
#pragma unroll
    for (int c = 0; c < 16; ++c) {
      const float4 w = wrow[c];
      asm volatile("v_accvgpr_write_b32 %0, %1" : "=a"(wg_a[4 * c + 0]) : "v"(w.x));
      asm volatile("v_accvgpr_write_b32 %0, %1" : "=a"(wg_a[4 * c + 1]) : "v"(w.y));
      asm volatile("v_accvgpr_write_b32 %0, %1" : "=a"(wg_a[4 * c + 2]) : "v"(w.z));
      asm volatile("v_accvgpr_write_b32 %0, %1" : "=a"(wg_a[4 * c + 3]) : "v"(w.w));
    }
  }
  const float bgj = bgp[j];
  const float bcj = bcp[jc];

  const int l0 = LEN[row0 + 0], l1 = LEN[row0 + 1];
  const int l2 = LEN[row0 + 2], l3 = LEN[row0 + 3];
  int maxlen = max(max(l0, l1), max(l2, l3));
  if (maxlen > TT) maxlen = TT;
  const int mylen = (r4 == 0) ? l0 : (r4 == 1) ? l1 : (r4 == 2) ? l2 : l3;

  // prefetch x[0], att[0]
  float xn = 0.0f, an = 0.0f;
  if (tid < 512) xn = X[((row0 + r4) << 7) + jc];
  if (tid < 4)   an = ATT[row0 + tid];

  __syncthreads();

  for (int t = 0; t < maxlen; ++t) {
    // ---- phase0: build xh = [x, h] ----
    if (tid < 512) {
      lxh[(r4 << 8) + jc] = xn;
    } else {
      const int rr = (tid >> 7) - 4;
      lxh[(rr << 8) + 128 + jc] = lh[(rr << 7) + jc];
    }
    if (tid < 4) la[tid] = an;
    __syncthreads();

    // issue next-step prefetch early; latency hides under the FMA phases
    if (t + 1 < TT) {
      if (tid < 512) xn = X[((((t + 1) << 10) + row0 + r4) << 7) + jc];
      if (tid < 4)   an = ATT[((t + 1) << 10) + row0 + tid];
    }

    // ---- phase1: gate matvec partials (weights from AGPR, xh broadcast) ----
    {
      float a0 = 0.f, a1 = 0.f, a2 = 0.f, a3 = 0.f;
      const float4* p0 = (const float4*)(lxh + (kq << 6));
      const float4* p1 = (const float4*)(lxh + 256 + (kq << 6));
      const float4* p2 = (const float4*)(lxh + 512 + (kq << 6));
      const float4* p3 = (const float4*)(lxh + 768 + (kq << 6));
#pragma unroll
      for (int c = 0; c < 16; ++c) {
        float w0, w1, w2, w3;
        asm volatile("v_accvgpr_read_b32 %0, %1" : "=v"(w0) : "a"(wg_a[4 * c + 0]));
        asm volatile("v_accvgpr_read_b32 %0, %1" : "=v"(w1) : "a"(wg_a[4 * c + 1]));
        asm volatile("v_accvgpr_read_b32 %0, %1" : "=v"(w2) : "a"(wg_a[4 * c + 2]));
        asm volatile("v_accvgpr_read_b32 %0, %1" : "=v"(w3) : "a"(wg_a[4 * c + 3]));
        const float4 v0 = p0[c]; a0 += w0*v0.x + w1*v0.y + w2*v0.z + w3*v0.w;
        const float4 v1 = p1[c]; a1 += w0*v1.x + w1*v1.y + w2*v1.z + w3*v1.w;
        const float4 v2 = p2[c]; a2 += w0*v2.x + w1*v2.y + w2*v2.z + w3*v2.w;
        const float4 v3 = p3[c]; a3 += w0*v3.x + w1*v3.y + w2*v3.z + w3*v3.w;
      }
      // lp[r][kq][j] — lane-consecutive stores, conflict-free
      lp[(kq << 8) + j]        = a0;
      lp[((4 + kq) << 8) + j]  = a1;
      lp[((8 + kq) << 8) + j]  = a2;
      lp[((12 + kq) << 8) + j] = a3;
    }
    __syncthreads();

    // ---- phase2: reduce + sigmoid; build r*h into xh ----
    {
      const int r2 = kq;           // tid>>8
      const int base = r2 << 10;
      float s = lp[base + j] + lp[base + 256 + j] +
                lp[base + 512 + j] + lp[base + 768 + j] + bgj;
      const float sig = 1.0f / (1.0f + __expf(-s));
      if (j < 128) lxh[(r2 << 8) + 128 + j] = sig * lh[(r2 << 7) + j];
      else         lsu[(r2 << 7) + (j - 128)] = sig;
    }
    __syncthreads();

    // ---- phase3: candidate matvec partials (Wc from LDS) ----
    {
      float a0 = 0.f, a1 = 0.f, a2 = 0.f, a3 = 0.f;
      const int kb = kq8 << 5;
      const float4* p0 = (const float4*)(lxh + kb);
      const float4* p1 = (const float4*)(lxh + 256 + kb);
      const float4* p2 = (const float4*)(lxh + 512 + kb);
      const float4* p3 = (const float4*)(lxh + 768 + kb);
      const float4* wp = (const float4*)(lWc + ((kb >> 2) << 9) + (jc << 2));
#pragma unroll
      for (int c = 0; c < 8; ++c) {
        const float4 w = wp[c << 7];   // + c*512 floats
        const float4 v0 = p0[c]; a0 += w.x*v0.x + w.y*v0.y + w.z*v0.z + w.w*v0.w;
        const float4 v1 = p1[c]; a1 += w.x*v1.x + w.y*v1.y + w.z*v1.z + w.w*v1.w;
        const float4 v2 = p2[c]; a2 += w.x*v2.x + w.y*v2.y + w.z*v2.z + w.w*v2.w;
        const float4 v3 = p3[c]; a3 += w.x*v3.x + w.y*v3.y + w.z*v3.z + w.w*v3.w;
      }
      // lp[r][kq8][jc]
      lp[(kq8 << 7) + jc]        = a0;
      lp[((8 + kq8) << 7) + jc]  = a1;
      lp[((16 + kq8) << 7) + jc] = a2;
      lp[((24 + kq8) << 7) + jc] = a3;
    }
    __syncthreads();

    // ---- phase4: reduce + tanh + state update + output ----
    if (tid < 512) {
      const int base = r4 << 10;
      float s = bcj;
#pragma unroll
      for (int q = 0; q < 8; ++q) s += lp[base + (q << 7) + jc];
      const float e2 = __expf(2.0f * s);
      const float cc = (e2 - 1.0f) / (e2 + 1.0f);
      const float u  = (1.0f - la[r4]) * lsu[(r4 << 7) + jc];
      const float hold = lh[(r4 << 7) + jc];
      const float nh = u * hold + (1.0f - u) * cc;
      const bool m = (t < mylen);
      lh[(r4 << 7) + jc] = m ? nh : hold;
      OUT[(((t << 10) + row0 + r4) << 7) + jc] = m ? nh : 0.0f;
    }
    __syncthreads();
  }

  // zero-fill steps past maxlen (harness poisons d_out)
  for (int t = maxlen; t < TT; ++t) {
    if (tid < 128) {
      const int rr = tid >> 5;
      const int qq = tid & 31;
      *(float4*)(OUT + (((t << 10) + row0 + rr) << 7) + (qq << 2)) =
          make_float4(0.f, 0.f, 0.f, 0.f);
    }
  }
  // final hidden state hx at offset T*B*H
  if (tid < 512) {
    OUT[TT * BB * HH + ((row0 + r4) << 7) + jc] = lh[(r4 << 7) + jc];
  }
}

extern "C" void kernel_launch(void* const* d_in, const int* in_sizes, int n_in,
                              void* d_out, int out_size, void* d_ws, size_t ws_size,
                              hipStream_t stream) {
  const float* X   = (const float*)d_in[0];
  const float* ATT = (const float*)d_in[1];
  const int*   LEN = (const int*)d_in[2];
  const float* Wg  = (const float*)d_in[3];
  const float* bg  = (const float*)d_in[4];
  const float* Wc  = (const float*)d_in[5];
  const float* bc  = (const float*)d_in[6];
  float* OUT = (float*)d_out;

  const size_t shmem = (size_t)LDS_FLOATS * sizeof(float);
  static_assert(LDS_FLOATS * sizeof(float) <= 160 * 1024, "LDS over 160KiB");
  (void)hipFuncSetAttribute((const void*)gru_persist,
                            hipFuncAttributeMaxDynamicSharedMemorySize,
                            (int)shmem);
  gru_persist<<<dim3(256), dim3(1024), shmem, stream>>>(X, ATT, LEN, Wg, bg,
                                                        Wc, bc, OUT);
}